// Round 1
// baseline (4655.644 us; speedup 1.0000x reference)
//
#include <hip/hip_runtime.h>

// ---------------------------------------------------------------------------
// VectorQuantize: conv1d(s2) x2 -> l2norm -> nearest-codebook argmax
// Round 1: all-fp32 vector-ALU implementation (correctness-first).
// B=16, D_IN=1024, T=4096 -> t1=2048 -> t2=1024; CB 8192x512.
// ---------------------------------------------------------------------------

#define C_OUT 512

// Conv1d stride 2, pad 1, kernel 3, as implicit GEMM.
// Block: 64 co x 64 t for one batch. 256 threads, each 4co x 4t.
template <int C_IN, int T_IN, int T_OUT>
__global__ __launch_bounds__(256) void conv_s2(const float* __restrict__ x,
                                               const float* __restrict__ w,
                                               float* __restrict__ out) {
  const int t0 = blockIdx.x * 64;
  const int co0 = blockIdx.y * 64;
  const int b = blockIdx.z;
  const int tid = threadIdx.x;
  const int cx = tid & 15;   // co group (inner -> w_s b128 reads 2-way max)
  const int tx = tid >> 4;   // t group

  __shared__ float w_s[24 * 64];   // [r = ci'*3+k][co']
  __shared__ float x_s[8 * 132];   // [ci'][toff 0..128], pad stride 132

  float acc[4][4] = {};
  const long xbase = (long)b * C_IN * T_IN;

  for (int ci0 = 0; ci0 < C_IN; ci0 += 8) {
    // --- stage W chunk: w[co0+co'][ci0+ci'][k], r = ci'*3+k in [0,24)
    {
      const int co_ = tid >> 2;
      const int rbase = tid & 3;
      const float* wp = w + ((long)(co0 + co_) * C_IN + ci0) * 3;
#pragma unroll
      for (int q = 0; q < 6; q++) {
        const int r = rbase + 4 * q;
        w_s[r * 64 + co_] = wp[r];
      }
    }
    // --- stage X chunk: 8 rows x 129 positions (global 2*t0-1 .. 2*t0+127)
    {
      const int half = tid >> 7;       // 0..1
      const int tf = tid & 127;
#pragma unroll
      for (int rr = 0; rr < 4; rr++) {
        const int cip = half + 2 * rr;
        const float* xp = x + xbase + (long)(ci0 + cip) * T_IN;
        const int p = 2 * t0 - 1 + tf;
        x_s[cip * 132 + tf] = (p >= 0 && p < T_IN) ? xp[p] : 0.0f;
        if (tf == 0) {
          const int p2 = 2 * t0 + 127;
          x_s[cip * 132 + 128] = (p2 < T_IN) ? xp[p2] : 0.0f;
        }
      }
    }
    __syncthreads();

#pragma unroll
    for (int cip = 0; cip < 8; cip++) {
      // 9 needed x values (offsets 2j+k in [0,8]) via contiguous vector reads
      const float* xs = &x_s[cip * 132 + 8 * tx];
      const float4 xa = *(const float4*)(xs);
      const float4 xb = *(const float4*)(xs + 4);
      const float2 xc = *(const float2*)(xs + 8);
      float xr[10] = {xa.x, xa.y, xa.z, xa.w, xb.x, xb.y, xb.z, xb.w, xc.x, xc.y};
#pragma unroll
      for (int k = 0; k < 3; k++) {
        const float4 wf = *(const float4*)&w_s[(cip * 3 + k) * 64 + cx * 4];
        const float wv[4] = {wf.x, wf.y, wf.z, wf.w};
#pragma unroll
        for (int i = 0; i < 4; i++)
#pragma unroll
          for (int j = 0; j < 4; j++)
            acc[i][j] = fmaf(wv[i], xr[2 * j + k], acc[i][j]);
      }
    }
    __syncthreads();
  }

#pragma unroll
  for (int i = 0; i < 4; i++) {
    const long o = ((long)b * C_OUT + (co0 + cx * 4 + i)) * T_OUT + t0 + tx * 4;
    *(float4*)(out + o) = make_float4(acc[i][0], acc[i][1], acc[i][2], acc[i][3]);
  }
}

// Transpose [b, d=512, t=1024] -> enc[(b*1024+t), d] with row L2-normalize.
__global__ __launch_bounds__(256) void norm_enc(const float* __restrict__ out2,
                                                float* __restrict__ enc) {
  const int b = blockIdx.y;
  const int t0 = blockIdx.x * 64;
  const int tid = threadIdx.x;
  __shared__ float ssred[4][64];
  __shared__ float norms[64];
  __shared__ float tile[64][65];

  const int tt = tid & 63, dp = tid >> 6;
  const float* base = out2 + (long)b * 512 * 1024 + t0;

  float ss = 0.0f;
  for (int d = dp; d < 512; d += 4) {
    const float v = base[(long)d * 1024 + tt];
    ss = fmaf(v, v, ss);
  }
  ssred[dp][tt] = ss;
  __syncthreads();
  if (tid < 64) {
    const float s = ssred[0][tid] + ssred[1][tid] + ssred[2][tid] + ssred[3][tid];
    norms[tid] = fmaxf(sqrtf(s), 1e-12f);
  }
  __syncthreads();

  for (int d0 = 0; d0 < 512; d0 += 64) {
#pragma unroll
    for (int q = 0; q < 16; q++) {
      const int dd = dp + 4 * q;
      tile[dd][tt] = base[(long)(d0 + dd) * 1024 + tt];
    }
    __syncthreads();
#pragma unroll
    for (int u = 0; u < 16; u++) {
      const int tl = (tid >> 6) + 4 * u;
      const int dl = tid & 63;
      const float v = tile[dl][tl] / norms[tl];
      enc[((long)(b * 1024 + t0 + tl)) * 512 + d0 + dl] = v;
    }
    __syncthreads();
  }
}

// Normalize codebook rows; also emit sum(cbn^2) per row (post-rounding, faithful).
__global__ __launch_bounds__(256) void norm_cb(const float* __restrict__ cb,
                                               float* __restrict__ cbn,
                                               float* __restrict__ cb2) {
  const int row = blockIdx.x * 4 + (threadIdx.x >> 6);
  const int lane = threadIdx.x & 63;
  const float* p = cb + (long)row * 512;
  const float4 v0 = *(const float4*)(p + lane * 4);
  const float4 v1 = *(const float4*)(p + 256 + lane * 4);
  float ss = v0.x * v0.x + v0.y * v0.y + v0.z * v0.z + v0.w * v0.w +
             v1.x * v1.x + v1.y * v1.y + v1.z * v1.z + v1.w * v1.w;
#pragma unroll
  for (int m = 32; m >= 1; m >>= 1) ss += __shfl_xor(ss, m, 64);
  const float n = fmaxf(sqrtf(ss), 1e-12f);
  float4 a, c;
  a.x = v0.x / n; a.y = v0.y / n; a.z = v0.z / n; a.w = v0.w / n;
  c.x = v1.x / n; c.y = v1.y / n; c.z = v1.z / n; c.w = v1.w / n;
  *(float4*)(cbn + (long)row * 512 + lane * 4) = a;
  *(float4*)(cbn + (long)row * 512 + 256 + lane * 4) = c;
  float s2 = a.x * a.x + a.y * a.y + a.z * a.z + a.w * a.w +
             c.x * c.x + c.y * c.y + c.z * c.z + c.w * c.w;
#pragma unroll
  for (int m = 32; m >= 1; m >>= 1) s2 += __shfl_xor(s2, m, 64);
  if (lane == 0) cb2[row] = s2;
}

// Distance GEMM tile (64 rows x 64 codes) + fused per-tile argmax partial.
// score = 2*dot - |cb|^2  (per-row |enc|^2 constant dropped); max == argmax(-dist).
__global__ __launch_bounds__(256) void dist_argmax_part(
    const float* __restrict__ enc, const float* __restrict__ cbn,
    const float* __restrict__ cb2, float* __restrict__ pscore,
    int* __restrict__ pidx) {
  const int n0 = blockIdx.x * 64;
  const int m0 = blockIdx.y * 64;
  const int tid = threadIdx.x;
  const int nx = tid & 15, mx = tid >> 4;

  __shared__ float a_s[16 * 68];  // [k][m], pad 68
  __shared__ float b_s[16 * 68];  // [k][n]
  __shared__ float rs[64][17];
  __shared__ int ri[64][17];

  float acc[4][4] = {};
  const int kt = tid & 15;
  const int rt = tid >> 4;

  for (int k0 = 0; k0 < 512; k0 += 16) {
#pragma unroll
    for (int q = 0; q < 4; q++) {
      const int r = rt + 16 * q;
      a_s[kt * 68 + r] = enc[(long)(m0 + r) * 512 + k0 + kt];
      b_s[kt * 68 + r] = cbn[(long)(n0 + r) * 512 + k0 + kt];
    }
    __syncthreads();
#pragma unroll
    for (int kk = 0; kk < 16; kk++) {
      const float4 af = *(const float4*)&a_s[kk * 68 + mx * 4];
      const float4 bf = *(const float4*)&b_s[kk * 68 + nx * 4];
      const float av[4] = {af.x, af.y, af.z, af.w};
      const float bv[4] = {bf.x, bf.y, bf.z, bf.w};
#pragma unroll
      for (int i = 0; i < 4; i++)
#pragma unroll
        for (int j = 0; j < 4; j++)
          acc[i][j] = fmaf(av[i], bv[j], acc[i][j]);
    }
    __syncthreads();
  }

#pragma unroll
  for (int i = 0; i < 4; i++) {
    float best = 0.0f;
    int bi = -1;
#pragma unroll
    for (int j = 0; j < 4; j++) {
      const int n = n0 + nx * 4 + j;
      const float s = 2.0f * acc[i][j] - cb2[n];
      if (bi < 0 || s > best) { best = s; bi = n; }  // ascending scan, strict >
    }
    rs[mx * 4 + i][nx] = best;
    ri[mx * 4 + i][nx] = bi;
  }
  __syncthreads();
  if (tid < 64) {
    float best = rs[tid][0];
    int bi = ri[tid][0];
#pragma unroll
    for (int e = 1; e < 16; e++) {
      const float s = rs[tid][e];
      if (s > best) { best = s; bi = ri[tid][e]; }  // strict >: keeps lowest n
    }
    const int row = m0 + tid;
    pscore[(long)row * 128 + blockIdx.x] = best;
    pidx[(long)row * 128 + blockIdx.x] = bi;
  }
}

// Final reduce over the 128 code-tiles per row, first-max tie-break.
__global__ __launch_bounds__(64) void argmax_final(const float* __restrict__ pscore,
                                                   const int* __restrict__ pidx,
                                                   int* __restrict__ out) {
  const int row = blockIdx.x;
  const int lane = threadIdx.x;
  const float* ps = pscore + (long)row * 128;
  const int* pi = pidx + (long)row * 128;
  float s0 = ps[lane];
  int i0 = pi[lane];
  const float s1 = ps[lane + 64];
  const int i1 = pi[lane + 64];
  if (s1 > s0 || (s1 == s0 && i1 < i0)) { s0 = s1; i0 = i1; }
#pragma unroll
  for (int m = 32; m >= 1; m >>= 1) {
    const float so = __shfl_xor(s0, m, 64);
    const int io = __shfl_xor(i0, m, 64);
    if (so > s0 || (so == s0 && io < i0)) { s0 = so; i0 = io; }
  }
  if (lane == 0) out[row] = i0;
}

extern "C" void kernel_launch(void* const* d_in, const int* in_sizes, int n_in,
                              void* d_out, int out_size, void* d_ws, size_t ws_size,
                              hipStream_t stream) {
  const float* x = (const float*)d_in[0];    // [16,1024,4096]
  const float* w1 = (const float*)d_in[1];   // [512,1024,3]
  const float* w2 = (const float*)d_in[2];   // [512,512,3]
  const float* cb = (const float*)d_in[3];   // [8192,512]
  int* out = (int*)d_out;                    // [16,1024] int32

  float* ws = (float*)d_ws;
  float* out1 = ws;                       // 16*512*2048 = 16777216
  float* out2 = out1 + 16777216;          // 16*512*1024 =  8388608
  float* enc = out2 + 8388608;            //               8388608
  float* cbn = enc + 8388608;             //               4194304
  float* cb2 = cbn + 4194304;             //                  8192
  float* pscore = cb2 + 8192;             // 16384*128  =  2097152
  int* pidx = (int*)(pscore + 2097152);   //               2097152
  // total ~168 MB of workspace

  conv_s2<1024, 4096, 2048><<<dim3(32, 8, 16), 256, 0, stream>>>(x, w1, out1);
  conv_s2<512, 2048, 1024><<<dim3(16, 8, 16), 256, 0, stream>>>(out1, w2, out2);
  norm_enc<<<dim3(16, 16), 256, 0, stream>>>(out2, enc);
  norm_cb<<<2048, 256, 0, stream>>>(cb, cbn, cb2);
  dist_argmax_part<<<dim3(128, 256), 256, 0, stream>>>(enc, cbn, cb2, pscore, pidx);
  argmax_final<<<16384, 64, 0, stream>>>(pscore, pidx, out);
}

// Round 2
// 3466.141 us; speedup vs baseline: 1.3432x; 1.3432x over previous
//
#include <hip/hip_runtime.h>

// ---------------------------------------------------------------------------
// VectorQuantize: conv1d(s2) x2 -> l2norm -> nearest-codebook argmax
// Round 2: distance stage on bf16 MFMA (approx top-2/tile) + exact fp32
// top-8 rescore. Convs still fp32 vector ALU (next round: fp16-split MFMA).
// ---------------------------------------------------------------------------

#define C_OUT 512

typedef __attribute__((ext_vector_type(8))) short bf16x8;
typedef __attribute__((ext_vector_type(4))) float f32x4;

__device__ inline ushort f2bf(float x) {
  union { float f; unsigned u; } v; v.f = x;
  unsigned r = v.u + 0x7fffu + ((v.u >> 16) & 1u);  // round-to-nearest-even
  return (ushort)(r >> 16);
}

// Conv1d stride 2, pad 1, kernel 3, as implicit GEMM (fp32).
template <int C_IN, int T_IN, int T_OUT>
__global__ __launch_bounds__(256) void conv_s2(const float* __restrict__ x,
                                               const float* __restrict__ w,
                                               float* __restrict__ out) {
  const int t0 = blockIdx.x * 64;
  const int co0 = blockIdx.y * 64;
  const int b = blockIdx.z;
  const int tid = threadIdx.x;
  const int cx = tid & 15;
  const int tx = tid >> 4;

  __shared__ float w_s[24 * 64];
  __shared__ float x_s[8 * 132];

  float acc[4][4] = {};
  const long xbase = (long)b * C_IN * T_IN;

  for (int ci0 = 0; ci0 < C_IN; ci0 += 8) {
    {
      const int co_ = tid >> 2;
      const int rbase = tid & 3;
      const float* wp = w + ((long)(co0 + co_) * C_IN + ci0) * 3;
#pragma unroll
      for (int q = 0; q < 6; q++) {
        const int r = rbase + 4 * q;
        w_s[r * 64 + co_] = wp[r];
      }
    }
    {
      const int half = tid >> 7;
      const int tf = tid & 127;
#pragma unroll
      for (int rr = 0; rr < 4; rr++) {
        const int cip = half + 2 * rr;
        const float* xp = x + xbase + (long)(ci0 + cip) * T_IN;
        const int p = 2 * t0 - 1 + tf;
        x_s[cip * 132 + tf] = (p >= 0 && p < T_IN) ? xp[p] : 0.0f;
        if (tf == 0) {
          const int p2 = 2 * t0 + 127;
          x_s[cip * 132 + 128] = (p2 < T_IN) ? xp[p2] : 0.0f;
        }
      }
    }
    __syncthreads();

#pragma unroll
    for (int cip = 0; cip < 8; cip++) {
      const float* xs = &x_s[cip * 132 + 8 * tx];
      const float4 xa = *(const float4*)(xs);
      const float4 xb = *(const float4*)(xs + 4);
      const float2 xc = *(const float2*)(xs + 8);
      float xr[10] = {xa.x, xa.y, xa.z, xa.w, xb.x, xb.y, xb.z, xb.w, xc.x, xc.y};
#pragma unroll
      for (int k = 0; k < 3; k++) {
        const float4 wf = *(const float4*)&w_s[(cip * 3 + k) * 64 + cx * 4];
        const float wv[4] = {wf.x, wf.y, wf.z, wf.w};
#pragma unroll
        for (int i = 0; i < 4; i++)
#pragma unroll
          for (int j = 0; j < 4; j++)
            acc[i][j] = fmaf(wv[i], xr[2 * j + k], acc[i][j]);
      }
    }
    __syncthreads();
  }

#pragma unroll
  for (int i = 0; i < 4; i++) {
    const long o = ((long)b * C_OUT + (co0 + cx * 4 + i)) * T_OUT + t0 + tx * 4;
    *(float4*)(out + o) = make_float4(acc[i][0], acc[i][1], acc[i][2], acc[i][3]);
  }
}

// Transpose [b,512,1024] -> enc[(b t),512] fp32 + enc16 bf16, L2-normalized.
__global__ __launch_bounds__(256) void norm_enc(const float* __restrict__ out2,
                                                float* __restrict__ enc,
                                                ushort* __restrict__ enc16) {
  const int b = blockIdx.y;
  const int t0 = blockIdx.x * 64;
  const int tid = threadIdx.x;
  __shared__ float ssred[4][64];
  __shared__ float norms[64];
  __shared__ float tile[64][65];

  const int tt = tid & 63, dp = tid >> 6;
  const float* base = out2 + (long)b * 512 * 1024 + t0;

  float ss = 0.0f;
  for (int d = dp; d < 512; d += 4) {
    const float v = base[(long)d * 1024 + tt];
    ss = fmaf(v, v, ss);
  }
  ssred[dp][tt] = ss;
  __syncthreads();
  if (tid < 64) {
    const float s = ssred[0][tid] + ssred[1][tid] + ssred[2][tid] + ssred[3][tid];
    norms[tid] = fmaxf(sqrtf(s), 1e-12f);
  }
  __syncthreads();

  for (int d0 = 0; d0 < 512; d0 += 64) {
#pragma unroll
    for (int q = 0; q < 16; q++) {
      const int dd = dp + 4 * q;
      tile[dd][tt] = base[(long)(d0 + dd) * 1024 + tt];
    }
    __syncthreads();
#pragma unroll
    for (int u = 0; u < 16; u++) {
      const int tl = (tid >> 6) + 4 * u;
      const int dl = tid & 63;
      const float v = tile[dl][tl] / norms[tl];
      const long o = ((long)(b * 1024 + t0 + tl)) * 512 + d0 + dl;
      enc[o] = v;
      enc16[o] = f2bf(v);
    }
    __syncthreads();
  }
}

// Normalize codebook rows (fp32 + bf16) and emit sum(cbn^2).
__global__ __launch_bounds__(256) void norm_cb(const float* __restrict__ cb,
                                               float* __restrict__ cbn,
                                               ushort* __restrict__ cbn16,
                                               float* __restrict__ cb2) {
  const int row = blockIdx.x * 4 + (threadIdx.x >> 6);
  const int lane = threadIdx.x & 63;
  const float* p = cb + (long)row * 512;
  const float4 v0 = *(const float4*)(p + lane * 4);
  const float4 v1 = *(const float4*)(p + 256 + lane * 4);
  float ss = v0.x * v0.x + v0.y * v0.y + v0.z * v0.z + v0.w * v0.w +
             v1.x * v1.x + v1.y * v1.y + v1.z * v1.z + v1.w * v1.w;
#pragma unroll
  for (int m = 32; m >= 1; m >>= 1) ss += __shfl_xor(ss, m, 64);
  const float n = fmaxf(sqrtf(ss), 1e-12f);
  float4 a, c;
  a.x = v0.x / n; a.y = v0.y / n; a.z = v0.z / n; a.w = v0.w / n;
  c.x = v1.x / n; c.y = v1.y / n; c.z = v1.z / n; c.w = v1.w / n;
  *(float4*)(cbn + (long)row * 512 + lane * 4) = a;
  *(float4*)(cbn + (long)row * 512 + 256 + lane * 4) = c;
  ushort4 ua, uc;
  ua.x = f2bf(a.x); ua.y = f2bf(a.y); ua.z = f2bf(a.z); ua.w = f2bf(a.w);
  uc.x = f2bf(c.x); uc.y = f2bf(c.y); uc.z = f2bf(c.z); uc.w = f2bf(c.w);
  *(ushort4*)(cbn16 + (long)row * 512 + lane * 4) = ua;
  *(ushort4*)(cbn16 + (long)row * 512 + 256 + lane * 4) = uc;
  float s2 = a.x * a.x + a.y * a.y + a.z * a.z + a.w * a.w +
             c.x * c.x + c.y * c.y + c.z * c.z + c.w * c.w;
#pragma unroll
  for (int m = 32; m >= 1; m >>= 1) s2 += __shfl_xor(s2, m, 64);
  if (lane == 0) cb2[row] = s2;
}

__device__ inline void top2_merge(float& s1, int& i1, float& s2, int& i2,
                                  float t1, int j1, float t2, int j2) {
  if (t1 > s1) {
    if (s1 > t2) { s2 = s1; i2 = i1; } else { s2 = t2; i2 = j2; }
    s1 = t1; i1 = j1;
  } else if (t1 > s2) {
    s2 = t1; i2 = j1;
  }
}

// 128x128 bf16 MFMA GEMM tile: approx score = 2*dot - |cb|^2, fused
// per-wave per-row top-2 -> 4 candidates/row/block (2 waves x top2).
__global__ __launch_bounds__(256) void score_top2(
    const ushort* __restrict__ enc16, const ushort* __restrict__ cbn16,
    const float* __restrict__ cb2, float* __restrict__ pscore,
    int* __restrict__ pidx) {
  const int nt = blockIdx.x;  // 64 tiles of 128 codes
  const int mt = blockIdx.y;  // 128 tiles of 128 rows
  const int m0 = mt * 128, n0 = nt * 128;
  const int tid = threadIdx.x;
  const int wave = tid >> 6, lane = tid & 63;
  const int wm = wave & 1, wn = wave >> 1;
  const int quad = lane >> 4, l15 = lane & 15;

  __shared__ ushort a_s[128 * 72];  // [row][k], K-stride 72 (pad) -> <=2-way
  __shared__ ushort b_s[128 * 72];

  f32x4 acc[4][4] = {};

  for (int k0 = 0; k0 < 512; k0 += 64) {
#pragma unroll
    for (int q = 0; q < 4; q++) {
      const int chunk = tid + 256 * q;  // 0..1023
      const int row = chunk >> 3, kb = chunk & 7;
      const uint4 va = *(const uint4*)(enc16 + (size_t)(m0 + row) * 512 + k0 + kb * 8);
      *(uint4*)(a_s + row * 72 + kb * 8) = va;
      const uint4 vb = *(const uint4*)(cbn16 + (size_t)(n0 + row) * 512 + k0 + kb * 8);
      *(uint4*)(b_s + row * 72 + kb * 8) = vb;
    }
    __syncthreads();
#pragma unroll
    for (int kk = 0; kk < 2; kk++) {
      bf16x8 af[4], bf[4];
#pragma unroll
      for (int i = 0; i < 4; i++)
        af[i] = *(const bf16x8*)(a_s + (wm * 64 + i * 16 + l15) * 72 + kk * 32 + quad * 8);
#pragma unroll
      for (int j = 0; j < 4; j++)
        bf[j] = *(const bf16x8*)(b_s + (wn * 64 + j * 16 + l15) * 72 + kk * 32 + quad * 8);
#pragma unroll
      for (int i = 0; i < 4; i++)
#pragma unroll
        for (int j = 0; j < 4; j++)
          acc[i][j] = __builtin_amdgcn_mfma_f32_16x16x32_bf16(af[i], bf[j], acc[i][j], 0, 0, 0);
    }
    __syncthreads();
  }

  // cb2 for this thread's 4 columns
  float cb2c[4];
  int coln[4];
#pragma unroll
  for (int j = 0; j < 4; j++) {
    coln[j] = n0 + wn * 64 + j * 16 + l15;
    cb2c[j] = cb2[coln[j]];
  }

  // per-row top-2 over this wave's 64 cols; rows: wm*64 + mi*16 + quad*4 + i
#pragma unroll
  for (int mi = 0; mi < 4; mi++) {
#pragma unroll
    for (int i = 0; i < 4; i++) {
      float s1 = -3.4e38f, s2 = -3.4e38f;
      int i1 = -1, i2 = -1;
#pragma unroll
      for (int j = 0; j < 4; j++) {
        const float s = 2.0f * acc[mi][j][i] - cb2c[j];
        if (s > s1) { s2 = s1; i2 = i1; s1 = s; i1 = coln[j]; }
        else if (s > s2) { s2 = s; i2 = coln[j]; }
      }
#pragma unroll
      for (int m = 8; m >= 1; m >>= 1) {
        const float t1 = __shfl_xor(s1, m, 64);
        const int j1 = __shfl_xor(i1, m, 64);
        const float t2 = __shfl_xor(s2, m, 64);
        const int j2 = __shfl_xor(i2, m, 64);
        top2_merge(s1, i1, s2, i2, t1, j1, t2, j2);
      }
      if (l15 == 0) {
        const int row_g = m0 + wm * 64 + mi * 16 + quad * 4 + i;
        const size_t base = (size_t)row_g * 256 + (size_t)nt * 4 + wn * 2;
        pscore[base] = s1; pidx[base] = i1;
        pscore[base + 1] = s2; pidx[base + 1] = i2;
      }
    }
  }
}

// Per row: approx top-8 of the 256 candidates, exact fp32 rescore, argmax.
__global__ __launch_bounds__(256) void rescore_argmax(
    const float* __restrict__ enc, const float* __restrict__ cbn,
    const float* __restrict__ cb2, const float* __restrict__ pscore,
    const int* __restrict__ pidx, int* __restrict__ out) {
  const int row = blockIdx.x;
  const int tid = threadIdx.x;
  __shared__ float wbest[4];
  __shared__ int wslot[4];
  __shared__ int winner;
  __shared__ int cand[8];
  __shared__ float fsc[8];
  __shared__ int fid[8];

  float s = pscore[(size_t)row * 256 + tid];
  const int id = pidx[(size_t)row * 256 + tid];

  for (int it = 0; it < 8; it++) {
    float bs = s;
    int bslot = tid;
#pragma unroll
    for (int m = 32; m >= 1; m >>= 1) {
      const float os = __shfl_xor(bs, m, 64);
      const int oslot = __shfl_xor(bslot, m, 64);
      if (os > bs || (os == bs && oslot < bslot)) { bs = os; bslot = oslot; }
    }
    if ((tid & 63) == 0) { wbest[tid >> 6] = bs; wslot[tid >> 6] = bslot; }
    __syncthreads();
    if (tid == 0) {
      float b = wbest[0]; int sl = wslot[0];
      for (int wv = 1; wv < 4; wv++)
        if (wbest[wv] > b || (wbest[wv] == b && wslot[wv] < sl)) { b = wbest[wv]; sl = wslot[wv]; }
      winner = sl;
    }
    __syncthreads();
    if (tid == winner) { cand[it] = id; s = -3.4e38f; }
    __syncthreads();
  }

  const int c = cand[tid >> 5];
  const float* ep = enc + (size_t)row * 512;
  const float* cp = cbn + (size_t)c * 512;
  float dot = 0.0f;
  const int d0 = (tid & 31) * 16;
#pragma unroll
  for (int u = 0; u < 4; u++) {
    const float4 e4 = *(const float4*)(ep + d0 + u * 4);
    const float4 c4 = *(const float4*)(cp + d0 + u * 4);
    dot = fmaf(e4.x, c4.x, dot);
    dot = fmaf(e4.y, c4.y, dot);
    dot = fmaf(e4.z, c4.z, dot);
    dot = fmaf(e4.w, c4.w, dot);
  }
#pragma unroll
  for (int m = 16; m >= 1; m >>= 1) dot += __shfl_xor(dot, m, 64);
  if ((tid & 31) == 0) {
    fsc[tid >> 5] = 2.0f * dot - cb2[c];
    fid[tid >> 5] = c;
  }
  __syncthreads();
  if (tid == 0) {
    float b = fsc[0]; int bi = fid[0];
    for (int q = 1; q < 8; q++)
      if (fsc[q] > b || (fsc[q] == b && fid[q] < bi)) { b = fsc[q]; bi = fid[q]; }
    out[row] = bi;
  }
}

extern "C" void kernel_launch(void* const* d_in, const int* in_sizes, int n_in,
                              void* d_out, int out_size, void* d_ws, size_t ws_size,
                              hipStream_t stream) {
  const float* x = (const float*)d_in[0];    // [16,1024,4096]
  const float* w1 = (const float*)d_in[1];   // [512,1024,3]
  const float* w2 = (const float*)d_in[2];   // [512,512,3]
  const float* cb = (const float*)d_in[3];   // [8192,512]
  int* out = (int*)d_out;                    // [16,1024] int32

  char* w0 = (char*)d_ws;
  // Region A (first 64MB): out1 during convs, then reused:
  float* out1 = (float*)w0;                              // 64MB (convs only)
  ushort* enc16 = (ushort*)w0;                           // [0,16MB)
  ushort* cbn16 = (ushort*)(w0 + (16ull << 20));         // [16,24MB)
  float* pscore = (float*)(w0 + (24ull << 20));          // [24,40MB)
  int* pidx = (int*)(w0 + (40ull << 20));                // [40,56MB)
  // Persistent regions:
  float* out2 = (float*)(w0 + (64ull << 20));            // [64,96MB)
  float* enc = (float*)(w0 + (96ull << 20));             // [96,128MB)
  float* cbn = (float*)(w0 + (128ull << 20));            // [128,144MB)
  float* cb2 = (float*)(w0 + (144ull << 20));            // 32KB

  conv_s2<1024, 4096, 2048><<<dim3(32, 8, 16), 256, 0, stream>>>(x, w1, out1);
  conv_s2<512, 2048, 1024><<<dim3(16, 8, 16), 256, 0, stream>>>(out1, w2, out2);
  // out1 dead from here; region A reused (stream-ordered).
  norm_enc<<<dim3(16, 16), 256, 0, stream>>>(out2, enc, enc16);
  norm_cb<<<2048, 256, 0, stream>>>(cb, cbn, cbn16, cb2);
  score_top2<<<dim3(64, 128), 256, 0, stream>>>(enc16, cbn16, cb2, pscore, pidx);
  rescore_argmax<<<16384, 256, 0, stream>>>(enc, cbn, cb2, pscore, pidx, out);
}

// Round 3
// 1917.065 us; speedup vs baseline: 2.4285x; 1.8080x over previous
//
#include <hip/hip_runtime.h>

// ---------------------------------------------------------------------------
// VectorQuantize: conv1d(s2) x2 -> l2norm -> nearest-codebook argmax
// Round 3: convs on f16-split MFMA (hh+hl+lh), phase-decomposed stride-2.
// Distance stage: bf16 MFMA top-2 + exact fp32 rescore (unchanged, passed).
// ---------------------------------------------------------------------------

typedef __attribute__((ext_vector_type(8))) _Float16 f16x8;
typedef __attribute__((ext_vector_type(8))) short bf16x8;
typedef __attribute__((ext_vector_type(4))) float f32x4;

__device__ inline ushort f2bf(float x) {
  union { float f; unsigned u; } v; v.f = x;
  unsigned r = v.u + 0x7fffu + ((v.u >> 16) & 1u);
  return (ushort)(r >> 16);
}

__device__ inline void splitf(float v, ushort& h, ushort& l) {
  union { _Float16 h; ushort u; } a, b;
  a.h = (_Float16)v;
  b.h = (_Float16)(v - (float)a.h);
  h = a.u; l = b.u;
}

// Split w[co][ci][3] fp32 -> ws[koff][hi/lo][co][ci] fp16.
__global__ __launch_bounds__(256) void prep_w(const float* __restrict__ w,
                                              ushort* __restrict__ ws,
                                              int n /* 512*cin */) {
  const int idx = blockIdx.x * 256 + threadIdx.x;
  if (idx >= n) return;
  const float v0 = w[(size_t)idx * 3 + 0];
  const float v1 = w[(size_t)idx * 3 + 1];
  const float v2 = w[(size_t)idx * 3 + 2];
  ushort h, l;
  splitf(v0, h, l); ws[idx] = h; ws[(size_t)n + idx] = l;
  splitf(v1, h, l); ws[2 * (size_t)n + idx] = h; ws[3 * (size_t)n + idx] = l;
  splitf(v2, h, l); ws[4 * (size_t)n + idx] = h; ws[5 * (size_t)n + idx] = l;
}

// Conv1d stride2 pad1 k3 as 3 phase GEMMs on fp16-split MFMA.
// Block: 128 co x 128 t, one batch. 4 waves, each 32co x 128t.
// TOUT=false: out[b][co][t] fp32.  TOUT=true: out[(b t)][co] fp32.
template <int C_IN, int T_IN, int T_OUT, bool TOUT>
__global__ __launch_bounds__(256, 3) void conv_mfma(
    const float* __restrict__ x, const ushort* __restrict__ ws,
    float* __restrict__ out) {
  const int co0 = blockIdx.x * 128;
  const int t0 = blockIdx.y * 128;
  const int b = blockIdx.z;
  const int tid = threadIdx.x;
  const int wv = tid >> 6;
  const int lane = tid & 63;
  const int l15 = lane & 15, quad = lane >> 4;

  constexpr int PX = 40;  // row stride (ushorts): 80B, keeps b128 reads aligned
  __shared__ ushort xe_hi[128 * PX], xe_lo[128 * PX];
  __shared__ ushort xo_hi[130 * PX], xo_lo[130 * PX];

  f32x4 acc[2][8] = {};
  const float* xb = x + (size_t)b * C_IN * T_IN;

  for (int ci0 = 0; ci0 < C_IN; ci0 += 32) {
    __syncthreads();
    {
      // stage x chunk: 32 ci x positions [2t0-1, 2t0+255], phase-split+fp16-split
      const int cg = tid & 3, tf = tid >> 2;  // tf 0..63: global coalescing
#pragma unroll
      for (int r = 0; r < 8; r++) {
        const int ci = cg * 8 + r;
        const float* xp = xb + (size_t)(ci0 + ci) * T_IN + 2 * t0 + 4 * tf;
        const float4 v = *(const float4*)xp;
        ushort h, l;
        splitf(v.x, h, l); xe_hi[(2 * tf) * PX + ci] = h; xe_lo[(2 * tf) * PX + ci] = l;
        splitf(v.y, h, l); xo_hi[(2 * tf + 1) * PX + ci] = h; xo_lo[(2 * tf + 1) * PX + ci] = l;
        splitf(v.z, h, l); xe_hi[(2 * tf + 1) * PX + ci] = h; xe_lo[(2 * tf + 1) * PX + ci] = l;
        splitf(v.w, h, l); xo_hi[(2 * tf + 2) * PX + ci] = h; xo_lo[(2 * tf + 2) * PX + ci] = l;
        if (tf == 0) {
          const float v0 = (t0 > 0) ? xp[-1] : 0.0f;
          splitf(v0, h, l); xo_hi[ci] = h; xo_lo[ci] = l;
        }
      }
    }
    __syncthreads();

#pragma unroll
    for (int koff = 0; koff < 3; koff++) {
      // A-fragments (W) straight from global; 16B contiguous per lane.
      f16x8 a_h[2], a_l[2];
#pragma unroll
      for (int i = 0; i < 2; i++) {
        const size_t co = (size_t)co0 + wv * 32 + i * 16 + l15;
        const ushort* wp = ws + ((size_t)(koff * 2) * 512 + co) * C_IN + ci0 + quad * 8;
        a_h[i] = *(const f16x8*)wp;
        a_l[i] = *(const f16x8*)(wp + (size_t)512 * C_IN);
      }
      const ushort* bh_arr = (koff == 1) ? xe_hi : xo_hi;
      const ushort* bl_arr = (koff == 1) ? xe_lo : xo_lo;
      const int radd = (koff == 2) ? 1 : 0;
#pragma unroll
      for (int j = 0; j < 8; j++) {
        const int row = j * 16 + l15 + radd;
        const f16x8 b_h = *(const f16x8*)(bh_arr + row * PX + quad * 8);
        const f16x8 b_l = *(const f16x8*)(bl_arr + row * PX + quad * 8);
#pragma unroll
        for (int i = 0; i < 2; i++) {
          acc[i][j] = __builtin_amdgcn_mfma_f32_16x16x32_f16(a_h[i], b_h, acc[i][j], 0, 0, 0);
          acc[i][j] = __builtin_amdgcn_mfma_f32_16x16x32_f16(a_h[i], b_l, acc[i][j], 0, 0, 0);
          acc[i][j] = __builtin_amdgcn_mfma_f32_16x16x32_f16(a_l[i], b_h, acc[i][j], 0, 0, 0);
        }
      }
    }
  }

#pragma unroll
  for (int i = 0; i < 2; i++) {
#pragma unroll
    for (int j = 0; j < 8; j++) {
      const int t = t0 + j * 16 + l15;
      const int co = co0 + wv * 32 + i * 16 + quad * 4;
      if (TOUT) {
        const float4 v = make_float4(acc[i][j][0], acc[i][j][1], acc[i][j][2], acc[i][j][3]);
        *(float4*)(out + ((size_t)b * T_OUT + t) * 512 + co) = v;
      } else {
#pragma unroll
        for (int r = 0; r < 4; r++)
          out[((size_t)b * 512 + co + r) * T_OUT + t] = acc[i][j][r];
      }
    }
  }
}

// Row-wise L2 normalize: out2t[(b t)][512] -> enc fp32 + enc16 bf16.
__global__ __launch_bounds__(64) void norm_rows(const float* __restrict__ out2t,
                                                float* __restrict__ enc,
                                                ushort* __restrict__ enc16) {
  const int row = blockIdx.x;
  const int lane = threadIdx.x;
  const float* p = out2t + (size_t)row * 512 + lane * 8;
  const float4 v0 = *(const float4*)p;
  const float4 v1 = *(const float4*)(p + 4);
  float ss = v0.x * v0.x + v0.y * v0.y + v0.z * v0.z + v0.w * v0.w +
             v1.x * v1.x + v1.y * v1.y + v1.z * v1.z + v1.w * v1.w;
#pragma unroll
  for (int m = 32; m >= 1; m >>= 1) ss += __shfl_xor(ss, m, 64);
  const float inv = 1.0f / fmaxf(sqrtf(ss), 1e-12f);
  float4 a, c;
  a.x = v0.x * inv; a.y = v0.y * inv; a.z = v0.z * inv; a.w = v0.w * inv;
  c.x = v1.x * inv; c.y = v1.y * inv; c.z = v1.z * inv; c.w = v1.w * inv;
  float* eo = enc + (size_t)row * 512 + lane * 8;
  *(float4*)eo = a;
  *(float4*)(eo + 4) = c;
  ushort u[8] = {f2bf(a.x), f2bf(a.y), f2bf(a.z), f2bf(a.w),
                 f2bf(c.x), f2bf(c.y), f2bf(c.z), f2bf(c.w)};
  *(uint4*)(enc16 + (size_t)row * 512 + lane * 8) = *(const uint4*)u;
}

// Normalize codebook rows (fp32 + bf16) and emit sum(cbn^2).
__global__ __launch_bounds__(256) void norm_cb(const float* __restrict__ cb,
                                               float* __restrict__ cbn,
                                               ushort* __restrict__ cbn16,
                                               float* __restrict__ cb2) {
  const int row = blockIdx.x * 4 + (threadIdx.x >> 6);
  const int lane = threadIdx.x & 63;
  const float* p = cb + (long)row * 512;
  const float4 v0 = *(const float4*)(p + lane * 4);
  const float4 v1 = *(const float4*)(p + 256 + lane * 4);
  float ss = v0.x * v0.x + v0.y * v0.y + v0.z * v0.z + v0.w * v0.w +
             v1.x * v1.x + v1.y * v1.y + v1.z * v1.z + v1.w * v1.w;
#pragma unroll
  for (int m = 32; m >= 1; m >>= 1) ss += __shfl_xor(ss, m, 64);
  const float n = fmaxf(sqrtf(ss), 1e-12f);
  float4 a, c;
  a.x = v0.x / n; a.y = v0.y / n; a.z = v0.z / n; a.w = v0.w / n;
  c.x = v1.x / n; c.y = v1.y / n; c.z = v1.z / n; c.w = v1.w / n;
  *(float4*)(cbn + (long)row * 512 + lane * 4) = a;
  *(float4*)(cbn + (long)row * 512 + 256 + lane * 4) = c;
  ushort4 ua, uc;
  ua.x = f2bf(a.x); ua.y = f2bf(a.y); ua.z = f2bf(a.z); ua.w = f2bf(a.w);
  uc.x = f2bf(c.x); uc.y = f2bf(c.y); uc.z = f2bf(c.z); uc.w = f2bf(c.w);
  *(ushort4*)(cbn16 + (long)row * 512 + lane * 4) = ua;
  *(ushort4*)(cbn16 + (long)row * 512 + 256 + lane * 4) = uc;
  float s2 = a.x * a.x + a.y * a.y + a.z * a.z + a.w * a.w +
             c.x * c.x + c.y * c.y + c.z * c.z + c.w * c.w;
#pragma unroll
  for (int m = 32; m >= 1; m >>= 1) s2 += __shfl_xor(s2, m, 64);
  if (lane == 0) cb2[row] = s2;
}

__device__ inline void top2_merge(float& s1, int& i1, float& s2, int& i2,
                                  float t1, int j1, float t2, int j2) {
  if (t1 > s1) {
    if (s1 > t2) { s2 = s1; i2 = i1; } else { s2 = t2; i2 = j2; }
    s1 = t1; i1 = j1;
  } else if (t1 > s2) {
    s2 = t1; i2 = j1;
  }
}

// 128x128 bf16 MFMA GEMM tile: approx score = 2*dot - |cb|^2, fused
// per-wave per-row top-2 -> 4 candidates/row/block.
__global__ __launch_bounds__(256) void score_top2(
    const ushort* __restrict__ enc16, const ushort* __restrict__ cbn16,
    const float* __restrict__ cb2, float* __restrict__ pscore,
    int* __restrict__ pidx) {
  const int nt = blockIdx.x;
  const int mt = blockIdx.y;
  const int m0 = mt * 128, n0 = nt * 128;
  const int tid = threadIdx.x;
  const int wave = tid >> 6, lane = tid & 63;
  const int wm = wave & 1, wn = wave >> 1;
  const int quad = lane >> 4, l15 = lane & 15;

  __shared__ ushort a_s[128 * 72];
  __shared__ ushort b_s[128 * 72];

  f32x4 acc[4][4] = {};

  for (int k0 = 0; k0 < 512; k0 += 64) {
#pragma unroll
    for (int q = 0; q < 4; q++) {
      const int chunk = tid + 256 * q;
      const int row = chunk >> 3, kb = chunk & 7;
      const uint4 va = *(const uint4*)(enc16 + (size_t)(m0 + row) * 512 + k0 + kb * 8);
      *(uint4*)(a_s + row * 72 + kb * 8) = va;
      const uint4 vb = *(const uint4*)(cbn16 + (size_t)(n0 + row) * 512 + k0 + kb * 8);
      *(uint4*)(b_s + row * 72 + kb * 8) = vb;
    }
    __syncthreads();
#pragma unroll
    for (int kk = 0; kk < 2; kk++) {
      bf16x8 af[4], bf[4];
#pragma unroll
      for (int i = 0; i < 4; i++)
        af[i] = *(const bf16x8*)(a_s + (wm * 64 + i * 16 + l15) * 72 + kk * 32 + quad * 8);
#pragma unroll
      for (int j = 0; j < 4; j++)
        bf[j] = *(const bf16x8*)(b_s + (wn * 64 + j * 16 + l15) * 72 + kk * 32 + quad * 8);
#pragma unroll
      for (int i = 0; i < 4; i++)
#pragma unroll
        for (int j = 0; j < 4; j++)
          acc[i][j] = __builtin_amdgcn_mfma_f32_16x16x32_bf16(af[i], bf[j], acc[i][j], 0, 0, 0);
    }
    __syncthreads();
  }

  float cb2c[4];
  int coln[4];
#pragma unroll
  for (int j = 0; j < 4; j++) {
    coln[j] = n0 + wn * 64 + j * 16 + l15;
    cb2c[j] = cb2[coln[j]];
  }

#pragma unroll
  for (int mi = 0; mi < 4; mi++) {
#pragma unroll
    for (int i = 0; i < 4; i++) {
      float s1 = -3.4e38f, s2 = -3.4e38f;
      int i1 = -1, i2 = -1;
#pragma unroll
      for (int j = 0; j < 4; j++) {
        const float s = 2.0f * acc[mi][j][i] - cb2c[j];
        if (s > s1) { s2 = s1; i2 = i1; s1 = s; i1 = coln[j]; }
        else if (s > s2) { s2 = s; i2 = coln[j]; }
      }
#pragma unroll
      for (int m = 8; m >= 1; m >>= 1) {
        const float t1 = __shfl_xor(s1, m, 64);
        const int j1 = __shfl_xor(i1, m, 64);
        const float t2 = __shfl_xor(s2, m, 64);
        const int j2 = __shfl_xor(i2, m, 64);
        top2_merge(s1, i1, s2, i2, t1, j1, t2, j2);
      }
      if (l15 == 0) {
        const int row_g = m0 + wm * 64 + mi * 16 + quad * 4 + i;
        const size_t base = (size_t)row_g * 256 + (size_t)nt * 4 + wn * 2;
        pscore[base] = s1; pidx[base] = i1;
        pscore[base + 1] = s2; pidx[base + 1] = i2;
      }
    }
  }
}

// Per row: approx top-8 of 256 candidates, exact fp32 rescore, argmax.
__global__ __launch_bounds__(256) void rescore_argmax(
    const float* __restrict__ enc, const float* __restrict__ cbn,
    const float* __restrict__ cb2, const float* __restrict__ pscore,
    const int* __restrict__ pidx, int* __restrict__ out) {
  const int row = blockIdx.x;
  const int tid = threadIdx.x;
  __shared__ float wbest[4];
  __shared__ int wslot[4];
  __shared__ int winner;
  __shared__ int cand[8];
  __shared__ float fsc[8];
  __shared__ int fid[8];

  float s = pscore[(size_t)row * 256 + tid];
  const int id = pidx[(size_t)row * 256 + tid];

  for (int it = 0; it < 8; it++) {
    float bs = s;
    int bslot = tid;
#pragma unroll
    for (int m = 32; m >= 1; m >>= 1) {
      const float os = __shfl_xor(bs, m, 64);
      const int oslot = __shfl_xor(bslot, m, 64);
      if (os > bs || (os == bs && oslot < bslot)) { bs = os; bslot = oslot; }
    }
    if ((tid & 63) == 0) { wbest[tid >> 6] = bs; wslot[tid >> 6] = bslot; }
    __syncthreads();
    if (tid == 0) {
      float b = wbest[0]; int sl = wslot[0];
      for (int wv = 1; wv < 4; wv++)
        if (wbest[wv] > b || (wbest[wv] == b && wslot[wv] < sl)) { b = wbest[wv]; sl = wslot[wv]; }
      winner = sl;
    }
    __syncthreads();
    if (tid == winner) { cand[it] = id; s = -3.4e38f; }
    __syncthreads();
  }

  const int c = cand[tid >> 5];
  const float* ep = enc + (size_t)row * 512;
  const float* cp = cbn + (size_t)c * 512;
  float dot = 0.0f;
  const int d0 = (tid & 31) * 16;
#pragma unroll
  for (int u = 0; u < 4; u++) {
    const float4 e4 = *(const float4*)(ep + d0 + u * 4);
    const float4 c4 = *(const float4*)(cp + d0 + u * 4);
    dot = fmaf(e4.x, c4.x, dot);
    dot = fmaf(e4.y, c4.y, dot);
    dot = fmaf(e4.z, c4.z, dot);
    dot = fmaf(e4.w, c4.w, dot);
  }
#pragma unroll
  for (int m = 16; m >= 1; m >>= 1) dot += __shfl_xor(dot, m, 64);
  if ((tid & 31) == 0) {
    fsc[tid >> 5] = 2.0f * dot - cb2[c];
    fid[tid >> 5] = c;
  }
  __syncthreads();
  if (tid == 0) {
    float b = fsc[0]; int bi = fid[0];
    for (int q = 1; q < 8; q++)
      if (fsc[q] > b || (fsc[q] == b && fid[q] < bi)) { b = fsc[q]; bi = fid[q]; }
    out[row] = bi;
  }
}

extern "C" void kernel_launch(void* const* d_in, const int* in_sizes, int n_in,
                              void* d_out, int out_size, void* d_ws, size_t ws_size,
                              hipStream_t stream) {
  const float* x = (const float*)d_in[0];    // [16,1024,4096]
  const float* w1 = (const float*)d_in[1];   // [512,1024,3]
  const float* w2 = (const float*)d_in[2];   // [512,512,3]
  const float* cb = (const float*)d_in[3];   // [8192,512]
  int* out = (int*)d_out;                    // [16,1024] int32

  char* w0 = (char*)d_ws;
  // Region A [0,64MB): out1 during convs; reused afterwards:
  float* out1 = (float*)w0;                              // [b][512][2048] fp32
  ushort* enc16 = (ushort*)w0;                           // [0,16MB)
  float* pscore = (float*)(w0 + (16ull << 20));          // [16,32MB)
  int* pidx = (int*)(w0 + (32ull << 20));                // [32,48MB)
  // Persistent:
  float* out2t = (float*)(w0 + (64ull << 20));           // [(b t)][512] fp32, 32MB
  float* enc = (float*)(w0 + (96ull << 20));             // 32MB
  float* cbn = (float*)(w0 + (128ull << 20));            // 16MB
  ushort* cbn16 = (ushort*)(w0 + (144ull << 20));        // 8MB
  float* cb2 = (float*)(w0 + (152ull << 20));            // 32KB
  ushort* ws1 = (ushort*)(w0 + (153ull << 20));          // 6MB
  ushort* ws2 = (ushort*)(w0 + (159ull << 20));          // 3MB

  prep_w<<<2048, 256, 0, stream>>>(w1, ws1, 512 * 1024);
  prep_w<<<1024, 256, 0, stream>>>(w2, ws2, 512 * 512);
  conv_mfma<1024, 4096, 2048, false><<<dim3(4, 16, 16), 256, 0, stream>>>(x, ws1, out1);
  conv_mfma<512, 2048, 1024, true><<<dim3(4, 8, 16), 256, 0, stream>>>(out1, ws2, out2t);
  norm_rows<<<16384, 64, 0, stream>>>(out2t, enc, enc16);
  norm_cb<<<2048, 256, 0, stream>>>(cb, cbn, cbn16, cb2);
  score_top2<<<dim3(64, 128), 256, 0, stream>>>(enc16, cbn16, cb2, pscore, pidx);
  rescore_argmax<<<16384, 256, 0, stream>>>(enc, cbn, cb2, pscore, pidx, out);
}

// Round 4
// 1747.855 us; speedup vs baseline: 2.6636x; 1.0968x over previous
//
#include <hip/hip_runtime.h>

// ---------------------------------------------------------------------------
// VectorQuantize: conv1d(s2) x2 -> l2norm -> nearest-codebook argmax
// Round 4: pre-split fp16 x (phase+hi/lo) in global; conv kernels do pure
// uint4 global->LDS staging + MFMA. conv1 emits its output already split in
// conv2's input layout. 64t x 128co tiles, 4 blocks/CU exact packing.
// Distance stage unchanged (bf16 MFMA top-2 + exact fp32 rescore).
// Workspace required: ~331 MiB.
// ---------------------------------------------------------------------------

typedef __attribute__((ext_vector_type(8))) _Float16 f16x8;
typedef __attribute__((ext_vector_type(8))) short bf16x8;
typedef __attribute__((ext_vector_type(4))) float f32x4;

__device__ inline ushort f2bf(float x) {
  union { float f; unsigned u; } v; v.f = x;
  unsigned r = v.u + 0x7fffu + ((v.u >> 16) & 1u);
  return (ushort)(r >> 16);
}

__device__ inline void splitf(float v, ushort& h, ushort& l) {
  union { _Float16 h; ushort u; } a, b;
  a.h = (_Float16)v;
  b.h = (_Float16)(v - (float)a.h);
  h = a.u; l = b.u;
}

// Split w[co][ci][3] fp32 -> ws[koff*2+part][co][ci] fp16.
__global__ __launch_bounds__(256) void prep_w(const float* __restrict__ w,
                                              ushort* __restrict__ ws,
                                              int n /* 512*cin */) {
  const int idx = blockIdx.x * 256 + threadIdx.x;
  if (idx >= n) return;
  const float v0 = w[(size_t)idx * 3 + 0];
  const float v1 = w[(size_t)idx * 3 + 1];
  const float v2 = w[(size_t)idx * 3 + 2];
  ushort h, l;
  splitf(v0, h, l); ws[idx] = h; ws[(size_t)n + idx] = l;
  splitf(v1, h, l); ws[2 * (size_t)n + idx] = h; ws[3 * (size_t)n + idx] = l;
  splitf(v2, h, l); ws[4 * (size_t)n + idx] = h; ws[5 * (size_t)n + idx] = l;
}

// Zero the odd-phase guard rows (t=-1) for both conv inputs.
__global__ __launch_bounds__(256) void zero_halo(ushort* __restrict__ xo1,
                                                 ushort* __restrict__ xo2) {
  const int b = blockIdx.x, tid = threadIdx.x;
  const uint4 z = make_uint4(0, 0, 0, 0);
  *(uint4*)(xo1 + (size_t)b * 2049 * 2048 + tid * 8) = z;
  if (tid < 128) *(uint4*)(xo2 + (size_t)b * 1025 * 1024 + tid * 8) = z;
}

// x[b][ci][T] fp32 -> phase-split fp16 hi/lo:
//   xe[b][t=0..T/2-1][ch][part][ci32]  (x[2t])
//   xo[b][row=1..T/2][ch][part][ci32]  (x[2row-1]; row 0 = zero guard)
template <int CI, int T>
__global__ __launch_bounds__(256) void prep_x(const float* __restrict__ x,
                                              ushort* __restrict__ xe,
                                              ushort* __restrict__ xo) {
  const int t0 = blockIdx.x * 256;
  const int ci0 = blockIdx.y * 32;
  const int b = blockIdx.z;
  const int tid = threadIdx.x;
  __shared__ float tile[32][257];
  const int wv = tid >> 6, lane = tid & 63;
  const float* xb = x + ((size_t)b * CI + ci0) * T + t0;
#pragma unroll
  for (int r = 0; r < 8; r++) {
    const int ci = r * 4 + wv;
    const float4 v = *(const float4*)(xb + (size_t)ci * T + lane * 4);
    tile[ci][lane * 4 + 0] = v.x; tile[ci][lane * 4 + 1] = v.y;
    tile[ci][lane * 4 + 2] = v.z; tile[ci][lane * 4 + 3] = v.w;
  }
  __syncthreads();
  const int jj = tid >> 1, ph = tid & 1;  // tl = tid: 2-way LDS reads (free)
  const int tl = 2 * jj + ph;
  __attribute__((aligned(16))) ushort h[32], l[32];
#pragma unroll
  for (int c = 0; c < 32; c++) splitf(tile[c][tl], h[c], l[c]);
  constexpr int TH = T / 2;
  constexpr int RW = CI * 2;  // ushorts per row
  ushort* dst;
  if (ph == 0) dst = xe + ((size_t)b * TH + (t0 >> 1) + jj) * RW;
  else dst = xo + ((size_t)b * (TH + 1) + (t0 >> 1) + jj + 1) * RW;
  dst += (ci0 >> 5) * 64;
#pragma unroll
  for (int k = 0; k < 4; k++) {
    *(uint4*)(dst + k * 8) = *(const uint4*)(h + k * 8);
    *(uint4*)(dst + 32 + k * 8) = *(const uint4*)(l + k * 8);
  }
}

// Conv1d stride2 pad1 k3 on fp16-split MFMA (hh+hl+lh), pre-split inputs.
// Block: 128co x 64t, 4 waves (each 32co x 64t). 4 blocks/CU.
// SPLIT_OUT: write output split into conv2's input layout (ye/yo);
// else write fp32 out[(b t)][512].
template <int C_IN, int T_OUT, bool SPLIT_OUT>
__global__ __launch_bounds__(256, 4) void conv_mfma(
    const ushort* __restrict__ xe, const ushort* __restrict__ xo,
    const ushort* __restrict__ ws, float* __restrict__ out,
    ushort* __restrict__ ye, ushort* __restrict__ yo) {
  const int co0 = blockIdx.x * 128;
  const int t0 = blockIdx.y * 64;
  const int b = blockIdx.z;
  const int tid = threadIdx.x;
  const int wv = tid >> 6, lane = tid & 63;
  const int l15 = lane & 15, quad = lane >> 4;

  // PX=40 ushorts: 80B row stride -> b128 frag reads 2-way (free), 16B aligned
  __shared__ ushort xeh[64 * 40], xel[64 * 40], xoh[65 * 40], xol[65 * 40];

  f32x4 acc[2][4] = {};
  const int RW = C_IN * 2;
  const ushort* xe_b = xe + ((size_t)b * T_OUT + t0) * RW;
  const ushort* xo_b = xo + ((size_t)b * (T_OUT + 1) + t0) * RW;

  for (int ci0 = 0; ci0 < C_IN; ci0 += 32) {
    __syncthreads();
    const int choff = (ci0 >> 5) * 64;
    // stage: 258 row-part units x 4 groups of 16B = 1032 lane-tasks
#pragma unroll
    for (int q = 0; q < 5; q++) {
      const int id = tid + 256 * q;
      if (id < 1032) {
        const int g = id & 3;
        const int u = id >> 2;
        const uint4* src;
        ushort* dst;
        if (u < 128) {
          const int row = u >> 1, part = u & 1;
          src = (const uint4*)(xe_b + (size_t)row * RW + choff + part * 32 + g * 8);
          dst = (part ? xel : xeh) + row * 40 + g * 8;
        } else {
          const int u2 = u - 128;
          const int row = u2 >> 1, part = u2 & 1;
          src = (const uint4*)(xo_b + (size_t)row * RW + choff + part * 32 + g * 8);
          dst = (part ? xol : xoh) + row * 40 + g * 8;
        }
        *(uint4*)dst = *src;
      }
    }
    __syncthreads();

#pragma unroll
    for (int koff = 0; koff < 3; koff++) {
      // A (W) fragments straight from global (L2/L3-resident)
      f16x8 a_h[2], a_l[2];
#pragma unroll
      for (int i = 0; i < 2; i++) {
        const size_t co = (size_t)co0 + wv * 32 + i * 16 + l15;
        const ushort* wp = ws + ((size_t)(koff * 2) * 512) * C_IN + co * C_IN + ci0 + quad * 8;
        a_h[i] = *(const f16x8*)wp;
        a_l[i] = *(const f16x8*)(wp + (size_t)512 * C_IN);
      }
      const ushort* bh = (koff == 1) ? xeh : xoh;
      const ushort* bl = (koff == 1) ? xel : xol;
      const int radd = (koff == 2) ? 1 : 0;
#pragma unroll
      for (int j = 0; j < 4; j++) {
        const int row = j * 16 + l15 + radd;
        const f16x8 b_h = *(const f16x8*)(bh + row * 40 + quad * 8);
        const f16x8 b_l = *(const f16x8*)(bl + row * 40 + quad * 8);
#pragma unroll
        for (int i = 0; i < 2; i++) {
          acc[i][j] = __builtin_amdgcn_mfma_f32_16x16x32_f16(a_h[i], b_h, acc[i][j], 0, 0, 0);
          acc[i][j] = __builtin_amdgcn_mfma_f32_16x16x32_f16(a_h[i], b_l, acc[i][j], 0, 0, 0);
          acc[i][j] = __builtin_amdgcn_mfma_f32_16x16x32_f16(a_l[i], b_h, acc[i][j], 0, 0, 0);
        }
      }
    }
  }

  if (SPLIT_OUT) {
    // write split fp16 into conv2's input layout (C=512 -> row = 1024 ush)
#pragma unroll
    for (int i = 0; i < 2; i++) {
      const int ch = (co0 >> 5) + wv;
      const int ci32 = i * 16 + quad * 4;
#pragma unroll
      for (int j = 0; j < 4; j++) {
        const int t = t0 + j * 16 + l15;
        const int ph = t & 1;
        const int row = (t >> 1) + ph;  // even -> ye[t/2]; odd -> yo[(t/2)+1]
        __attribute__((aligned(8))) ushort h[4], l[4];
#pragma unroll
        for (int r = 0; r < 4; r++) splitf(acc[i][j][r], h[r], l[r]);
        ushort* dst = (ph ? yo : ye) +
                      ((size_t)b * (ph ? 1025 : 1024) + row) * 1024 + ch * 64 + ci32;
        *(uint2*)dst = *(const uint2*)h;
        *(uint2*)(dst + 32) = *(const uint2*)l;
      }
    }
  } else {
#pragma unroll
    for (int i = 0; i < 2; i++) {
#pragma unroll
      for (int j = 0; j < 4; j++) {
        const int t = t0 + j * 16 + l15;
        const int co = co0 + wv * 32 + i * 16 + quad * 4;
        const float4 v = make_float4(acc[i][j][0], acc[i][j][1], acc[i][j][2], acc[i][j][3]);
        *(float4*)(out + ((size_t)b * T_OUT + t) * 512 + co) = v;
      }
    }
  }
}

// Row-wise L2 normalize: out2t[(b t)][512] -> enc fp32 + enc16 bf16.
__global__ __launch_bounds__(64) void norm_rows(const float* __restrict__ out2t,
                                                float* __restrict__ enc,
                                                ushort* __restrict__ enc16) {
  const int row = blockIdx.x;
  const int lane = threadIdx.x;
  const float* p = out2t + (size_t)row * 512 + lane * 8;
  const float4 v0 = *(const float4*)p;
  const float4 v1 = *(const float4*)(p + 4);
  float ss = v0.x * v0.x + v0.y * v0.y + v0.z * v0.z + v0.w * v0.w +
             v1.x * v1.x + v1.y * v1.y + v1.z * v1.z + v1.w * v1.w;
#pragma unroll
  for (int m = 32; m >= 1; m >>= 1) ss += __shfl_xor(ss, m, 64);
  const float inv = 1.0f / fmaxf(sqrtf(ss), 1e-12f);
  float4 a, c;
  a.x = v0.x * inv; a.y = v0.y * inv; a.z = v0.z * inv; a.w = v0.w * inv;
  c.x = v1.x * inv; c.y = v1.y * inv; c.z = v1.z * inv; c.w = v1.w * inv;
  float* eo = enc + (size_t)row * 512 + lane * 8;
  *(float4*)eo = a;
  *(float4*)(eo + 4) = c;
  __attribute__((aligned(16))) ushort u[8] = {
      f2bf(a.x), f2bf(a.y), f2bf(a.z), f2bf(a.w),
      f2bf(c.x), f2bf(c.y), f2bf(c.z), f2bf(c.w)};
  *(uint4*)(enc16 + (size_t)row * 512 + lane * 8) = *(const uint4*)u;
}

// Normalize codebook rows (fp32 + bf16) and emit sum(cbn^2).
__global__ __launch_bounds__(256) void norm_cb(const float* __restrict__ cb,
                                               float* __restrict__ cbn,
                                               ushort* __restrict__ cbn16,
                                               float* __restrict__ cb2) {
  const int row = blockIdx.x * 4 + (threadIdx.x >> 6);
  const int lane = threadIdx.x & 63;
  const float* p = cb + (long)row * 512;
  const float4 v0 = *(const float4*)(p + lane * 4);
  const float4 v1 = *(const float4*)(p + 256 + lane * 4);
  float ss = v0.x * v0.x + v0.y * v0.y + v0.z * v0.z + v0.w * v0.w +
             v1.x * v1.x + v1.y * v1.y + v1.z * v1.z + v1.w * v1.w;
#pragma unroll
  for (int m = 32; m >= 1; m >>= 1) ss += __shfl_xor(ss, m, 64);
  const float n = fmaxf(sqrtf(ss), 1e-12f);
  float4 a, c;
  a.x = v0.x / n; a.y = v0.y / n; a.z = v0.z / n; a.w = v0.w / n;
  c.x = v1.x / n; c.y = v1.y / n; c.z = v1.z / n; c.w = v1.w / n;
  *(float4*)(cbn + (long)row * 512 + lane * 4) = a;
  *(float4*)(cbn + (long)row * 512 + 256 + lane * 4) = c;
  ushort4 ua, uc;
  ua.x = f2bf(a.x); ua.y = f2bf(a.y); ua.z = f2bf(a.z); ua.w = f2bf(a.w);
  uc.x = f2bf(c.x); uc.y = f2bf(c.y); uc.z = f2bf(c.z); uc.w = f2bf(c.w);
  *(ushort4*)(cbn16 + (long)row * 512 + lane * 4) = ua;
  *(ushort4*)(cbn16 + (long)row * 512 + 256 + lane * 4) = uc;
  float s2 = a.x * a.x + a.y * a.y + a.z * a.z + a.w * a.w +
             c.x * c.x + c.y * c.y + c.z * c.z + c.w * c.w;
#pragma unroll
  for (int m = 32; m >= 1; m >>= 1) s2 += __shfl_xor(s2, m, 64);
  if (lane == 0) cb2[row] = s2;
}

__device__ inline void top2_merge(float& s1, int& i1, float& s2, int& i2,
                                  float t1, int j1, float t2, int j2) {
  if (t1 > s1) {
    if (s1 > t2) { s2 = s1; i2 = i1; } else { s2 = t2; i2 = j2; }
    s1 = t1; i1 = j1;
  } else if (t1 > s2) {
    s2 = t1; i2 = j1;
  }
}

// 128x128 bf16 MFMA GEMM tile: approx score = 2*dot - |cb|^2, fused
// per-wave per-row top-2 -> 4 candidates/row/block.
__global__ __launch_bounds__(256) void score_top2(
    const ushort* __restrict__ enc16, const ushort* __restrict__ cbn16,
    const float* __restrict__ cb2, float* __restrict__ pscore,
    int* __restrict__ pidx) {
  const int nt = blockIdx.x;
  const int mt = blockIdx.y;
  const int m0 = mt * 128, n0 = nt * 128;
  const int tid = threadIdx.x;
  const int wave = tid >> 6, lane = tid & 63;
  const int wm = wave & 1, wn = wave >> 1;
  const int quad = lane >> 4, l15 = lane & 15;

  __shared__ ushort a_s[128 * 72];
  __shared__ ushort b_s[128 * 72];

  f32x4 acc[4][4] = {};

  for (int k0 = 0; k0 < 512; k0 += 64) {
#pragma unroll
    for (int q = 0; q < 4; q++) {
      const int chunk = tid + 256 * q;
      const int row = chunk >> 3, kb = chunk & 7;
      const uint4 va = *(const uint4*)(enc16 + (size_t)(m0 + row) * 512 + k0 + kb * 8);
      *(uint4*)(a_s + row * 72 + kb * 8) = va;
      const uint4 vb = *(const uint4*)(cbn16 + (size_t)(n0 + row) * 512 + k0 + kb * 8);
      *(uint4*)(b_s + row * 72 + kb * 8) = vb;
    }
    __syncthreads();
#pragma unroll
    for (int kk = 0; kk < 2; kk++) {
      bf16x8 af[4], bf[4];
#pragma unroll
      for (int i = 0; i < 4; i++)
        af[i] = *(const bf16x8*)(a_s + (wm * 64 + i * 16 + l15) * 72 + kk * 32 + quad * 8);
#pragma unroll
      for (int j = 0; j < 4; j++)
        bf[j] = *(const bf16x8*)(b_s + (wn * 64 + j * 16 + l15) * 72 + kk * 32 + quad * 8);
#pragma unroll
      for (int i = 0; i < 4; i++)
#pragma unroll
        for (int j = 0; j < 4; j++)
          acc[i][j] = __builtin_amdgcn_mfma_f32_16x16x32_bf16(af[i], bf[j], acc[i][j], 0, 0, 0);
    }
    __syncthreads();
  }

  float cb2c[4];
  int coln[4];
#pragma unroll
  for (int j = 0; j < 4; j++) {
    coln[j] = n0 + wn * 64 + j * 16 + l15;
    cb2c[j] = cb2[coln[j]];
  }

#pragma unroll
  for (int mi = 0; mi < 4; mi++) {
#pragma unroll
    for (int i = 0; i < 4; i++) {
      float s1 = -3.4e38f, s2 = -3.4e38f;
      int i1 = -1, i2 = -1;
#pragma unroll
      for (int j = 0; j < 4; j++) {
        const float s = 2.0f * acc[mi][j][i] - cb2c[j];
        if (s > s1) { s2 = s1; i2 = i1; s1 = s; i1 = coln[j]; }
        else if (s > s2) { s2 = s; i2 = coln[j]; }
      }
#pragma unroll
      for (int m = 8; m >= 1; m >>= 1) {
        const float t1 = __shfl_xor(s1, m, 64);
        const int j1 = __shfl_xor(i1, m, 64);
        const float t2 = __shfl_xor(s2, m, 64);
        const int j2 = __shfl_xor(i2, m, 64);
        top2_merge(s1, i1, s2, i2, t1, j1, t2, j2);
      }
      if (l15 == 0) {
        const int row_g = m0 + wm * 64 + mi * 16 + quad * 4 + i;
        const size_t base = (size_t)row_g * 256 + (size_t)nt * 4 + wn * 2;
        pscore[base] = s1; pidx[base] = i1;
        pscore[base + 1] = s2; pidx[base + 1] = i2;
      }
    }
  }
}

// Per row: approx top-8 of 256 candidates, exact fp32 rescore, argmax.
__global__ __launch_bounds__(256) void rescore_argmax(
    const float* __restrict__ enc, const float* __restrict__ cbn,
    const float* __restrict__ cb2, const float* __restrict__ pscore,
    const int* __restrict__ pidx, int* __restrict__ out) {
  const int row = blockIdx.x;
  const int tid = threadIdx.x;
  __shared__ float wbest[4];
  __shared__ int wslot[4];
  __shared__ int winner;
  __shared__ int cand[8];
  __shared__ float fsc[8];
  __shared__ int fid[8];

  float s = pscore[(size_t)row * 256 + tid];
  const int id = pidx[(size_t)row * 256 + tid];

  for (int it = 0; it < 8; it++) {
    float bs = s;
    int bslot = tid;
#pragma unroll
    for (int m = 32; m >= 1; m >>= 1) {
      const float os = __shfl_xor(bs, m, 64);
      const int oslot = __shfl_xor(bslot, m, 64);
      if (os > bs || (os == bs && oslot < bslot)) { bs = os; bslot = oslot; }
    }
    if ((tid & 63) == 0) { wbest[tid >> 6] = bs; wslot[tid >> 6] = bslot; }
    __syncthreads();
    if (tid == 0) {
      float b = wbest[0]; int sl = wslot[0];
      for (int wv = 1; wv < 4; wv++)
        if (wbest[wv] > b || (wbest[wv] == b && wslot[wv] < sl)) { b = wbest[wv]; sl = wslot[wv]; }
      winner = sl;
    }
    __syncthreads();
    if (tid == winner) { cand[it] = id; s = -3.4e38f; }
    __syncthreads();
  }

  const int c = cand[tid >> 5];
  const float* ep = enc + (size_t)row * 512;
  const float* cp = cbn + (size_t)c * 512;
  float dot = 0.0f;
  const int d0 = (tid & 31) * 16;
#pragma unroll
  for (int u = 0; u < 4; u++) {
    const float4 e4 = *(const float4*)(ep + d0 + u * 4);
    const float4 c4 = *(const float4*)(cp + d0 + u * 4);
    dot = fmaf(e4.x, c4.x, dot);
    dot = fmaf(e4.y, c4.y, dot);
    dot = fmaf(e4.z, c4.z, dot);
    dot = fmaf(e4.w, c4.w, dot);
  }
#pragma unroll
  for (int m = 16; m >= 1; m >>= 1) dot += __shfl_xor(dot, m, 64);
  if ((tid & 31) == 0) {
    fsc[tid >> 5] = 2.0f * dot - cb2[c];
    fid[tid >> 5] = c;
  }
  __syncthreads();
  if (tid == 0) {
    float b = fsc[0]; int bi = fid[0];
    for (int q = 1; q < 8; q++)
      if (fsc[q] > b || (fsc[q] == b && fid[q] < bi)) { b = fsc[q]; bi = fid[q]; }
    out[row] = bi;
  }
}

extern "C" void kernel_launch(void* const* d_in, const int* in_sizes, int n_in,
                              void* d_out, int out_size, void* d_ws, size_t ws_size,
                              hipStream_t stream) {
  const float* x = (const float*)d_in[0];    // [16,1024,4096]
  const float* w1 = (const float*)d_in[1];   // [512,1024,3]
  const float* w2 = (const float*)d_in[2];   // [512,512,3]
  const float* cb = (const float*)d_in[3];   // [8192,512]
  int* out = (int*)d_out;                    // [16,1024] int32

  char* w0 = (char*)d_ws;
  const size_t MB = 1ull << 20;
  // Phase 1 (convs):
  ushort* xe1 = (ushort*)(w0);               // [0,128)   16*2048*2048 ush
  ushort* xo1 = (ushort*)(w0 + 128 * MB);    // [128,256.1) 16*2049*2048
  ushort* xe2 = (ushort*)(w0 + 257 * MB);    // [257,289)  16*1024*1024
  ushort* xo2 = (ushort*)(w0 + 289 * MB);    // [289,321.1) 16*1025*1024
  ushort* ws1 = (ushort*)(w0 + 322 * MB);    // 6 MiB
  ushort* ws2 = (ushort*)(w0 + 328 * MB);    // 3 MiB (ends 331 MiB)
  // Phase 2 (reuse [0,256) after conv1 is done):
  float* out2t = (float*)(w0);               // [0,32)
  float* enc = (float*)(w0 + 32 * MB);       // [32,64)
  ushort* enc16 = (ushort*)(w0 + 64 * MB);   // [64,80)
  float* cbn = (float*)(w0 + 80 * MB);       // [80,96)
  ushort* cbn16 = (ushort*)(w0 + 96 * MB);   // [96,104)
  float* cb2 = (float*)(w0 + 104 * MB);      // 32 KiB
  float* pscore = (float*)(w0 + 112 * MB);   // [112,128)
  int* pidx = (int*)(w0 + 128 * MB);         // [128,144) (xo1 dead by then)

  zero_halo<<<16, 256, 0, stream>>>(xo1, xo2);
  prep_w<<<2048, 256, 0, stream>>>(w1, ws1, 512 * 1024);
  prep_w<<<1024, 256, 0, stream>>>(w2, ws2, 512 * 512);
  prep_x<1024, 4096><<<dim3(16, 32, 16), 256, 0, stream>>>(x, xe1, xo1);
  conv_mfma<1024, 2048, true><<<dim3(4, 32, 16), 256, 0, stream>>>(
      xe1, xo1, ws1, nullptr, xe2, xo2);
  conv_mfma<512, 1024, false><<<dim3(4, 16, 16), 256, 0, stream>>>(
      xe2, xo2, ws2, out2t, nullptr, nullptr);
  norm_rows<<<16384, 64, 0, stream>>>(out2t, enc, enc16);
  norm_cb<<<2048, 256, 0, stream>>>(cb, cbn, cbn16, cb2);
  score_top2<<<dim3(64, 128), 256, 0, stream>>>(enc16, cbn16, cb2, pscore, pidx);
  rescore_argmax<<<16384, 256, 0, stream>>>(enc, cbn, cb2, pscore, pidx, out);
}